// Round 1
// baseline (1291.310 us; speedup 1.0000x reference)
//
#include <hip/hip_runtime.h>

#define IMG   512
#define TILE  128
#define BUF   160      // buffer rows & cols (tile + 2*16)
#define OFF   16       // buffer (0,0) <-> global (tile_origin - 16)
#define NPATCH 1014    // 39 col-patches x 26 row-bands

__device__ __forceinline__ float mapf(float g) {
    float t = 3.9f * g;
    return t - t * g;          // R*g*(1-g), fma-contracted
}

// Computes g = conv(K') . M + 0.15*drive for a 4-wide x 6-tall patch.
// Rows y0..y0+5, output cols xr+2..xr+5 (reads cols xr..xr+7, b128-aligned).
__device__ __forceinline__ void conv_rows(
    const float (&lds)[BUF][BUF], int y0, int xr,
    const float* kk, const float* dv, float* g)
{
    float4 aL = *(const float4*)&lds[y0-1][xr];
    float4 aH = *(const float4*)&lds[y0-1][xr+4];
    float4 bL = *(const float4*)&lds[y0  ][xr];
    float4 bH = *(const float4*)&lds[y0  ][xr+4];
#pragma unroll
    for (int rr = 0; rr < 6; rr++) {
        float4 cL = *(const float4*)&lds[y0+1+rr][xr];
        float4 cH = *(const float4*)&lds[y0+1+rr][xr+4];
        const float a[8] = {aL.x,aL.y,aL.z,aL.w,aH.x,aH.y,aH.z,aH.w};
        const float b[8] = {bL.x,bL.y,bL.z,bL.w,bH.x,bH.y,bH.z,bH.w};
        const float c[8] = {cL.x,cL.y,cL.z,cL.w,cH.x,cH.y,cH.z,cH.w};
#pragma unroll
        for (int k = 0; k < 4; k++) {
            float s;
            s  = kk[0]*a[k+1] + kk[1]*a[k+2] + kk[2]*a[k+3];
            s += kk[3]*b[k+1] + kk[4]*b[k+2] + kk[5]*b[k+3];
            s += kk[6]*c[k+1] + kk[7]*c[k+2] + kk[8]*c[k+3];
            g[rr*4+k] = s + 0.15f*dv[rr*4+k];
        }
        aL = bL; aH = bH; bL = cL; bH = cH;
    }
}

__global__ __launch_bounds__(1024) void cml_fused(
    const float* __restrict__ drive,
    const float* __restrict__ Kw,
    float* __restrict__ out)
{
    __shared__ float lds[BUF][BUF];   // 100 KiB

    const int tid = threadIdx.x;
    const int bid = blockIdx.x;
    const int bc  = bid >> 4;               // image index (b*4+c), 0..255
    const int tl  = bid & 15;               // 4x4 tiles of 128x128
    const int ty0 = (tl >> 2) * TILE;
    const int tx0 = (tl & 3)  * TILE;
    const int gy0 = ty0 - OFF;              // buffer row r <-> global gy0+r
    const int gx0 = tx0 - OFF;
    const float* __restrict__ img  = drive + (size_t)bc * (IMG * IMG);
    float* __restrict__ oimg       = out   + (size_t)bc * (IMG * IMG);

    // Folded 3x3 kernel: K' = (0.85*0.3)*K + (0.85*0.7)*delta_center
    float kk[9];
    {
        const float c2 = 0.85f * 0.3f;
        const float* kp = Kw + (bc & 3) * 9;
#pragma unroll
        for (int q = 0; q < 9; q++) kk[q] = c2 * kp[q];
        kk[4] += 0.85f * 0.7f;
    }

    const bool active = tid < NPATCH;
    const int pi = tid / 39;                // row band 0..25
    const int pj = tid - pi * 39;           // col patch 0..38
    const int y0 = 2 + 6 * pi;              // output rows y0..y0+5
    const int xr = 4 * pj;                  // read base col (outputs xr+2..xr+5)

    // In-image flags per output column (loop-invariant)
    float fx[4];
#pragma unroll
    for (int k = 0; k < 4; k++)
        fx[k] = ((unsigned)(gx0 + xr + 2 + k) < IMG) ? 1.0f : 0.0f;

    // Drive for my patch cells, in registers (exact fp32)
    float dv[24];
#pragma unroll
    for (int rr = 0; rr < 6; rr++) {
        const int gy = gy0 + y0 + rr;
#pragma unroll
        for (int k = 0; k < 4; k++) {
            const int gx = gx0 + xr + 2 + k;
            dv[rr*4+k] = ((unsigned)gy < IMG && (unsigned)gx < IMG)
                       ? img[gy * IMG + gx] : 0.0f;
        }
    }

    // Init: M1 = map(drive) over full 160x160 buffer (out-of-image -> 0 -> map 0)
    for (int u = tid; u < (BUF*BUF)/4; u += 1024) {
        const int yy = u / (BUF/4);
        const int xx = (u - yy * (BUF/4)) * 4;
        const int gy  = gy0 + yy;
        const int gxb = gx0 + xx;                 // multiple of 4 -> aligned float4
        float4 v = make_float4(0.f, 0.f, 0.f, 0.f);
        if ((unsigned)gy < IMG && (unsigned)gxb < IMG)
            v = *(const float4*)(img + gy * IMG + gxb);
        v.x = mapf(v.x); v.y = mapf(v.y); v.z = mapf(v.z); v.w = mapf(v.w);
        *(float4*)&lds[yy][xx] = v;
    }
    __syncthreads();

    float st[24];
#pragma unroll 1
    for (int step = 0; step < 14; step++) {
        if (active) {
            conv_rows(lds, y0, xr, kk, dv, st);   // st = grid values
            // map + zero-pad flags -> st = M_{t+1}
#pragma unroll
            for (int rr = 0; rr < 6; rr++) {
                const float fy = ((unsigned)(gy0 + y0 + rr) < IMG) ? 1.0f : 0.0f;
#pragma unroll
                for (int k = 0; k < 4; k++) {
                    const float g = st[rr*4+k];
                    const float t = 3.9f * g;
                    st[rr*4+k] = (t - t * g) * (fy * fx[k]);
                }
            }
        }
        __syncthreads();   // all reads done before any write
        if (active) {
#pragma unroll
            for (int rr = 0; rr < 6; rr++) {
                *(float2*)&lds[y0+rr][xr+2] = make_float2(st[rr*4+0], st[rr*4+1]);
                *(float2*)&lds[y0+rr][xr+4] = make_float2(st[rr*4+2], st[rr*4+3]);
            }
        }
        __syncthreads();   // writes done before next step's reads
    }

    // Step 15: compute grid, clip, store tile directly to global
    if (active) {
        conv_rows(lds, y0, xr, kk, dv, st);
#pragma unroll
        for (int rr = 0; rr < 6; rr++) {
            const int r = y0 + rr;
            if (r >= OFF && r < OFF + TILE) {
#pragma unroll
                for (int k = 0; k < 4; k++) {
                    const int x = xr + 2 + k;
                    if (x >= OFF && x < OFF + TILE) {
                        float g = st[rr*4+k];
                        g = fminf(fmaxf(g, 1e-4f), 1.0f - 1e-4f);
                        oimg[(gy0 + r) * IMG + (gx0 + x)] = g;
                    }
                }
            }
        }
    }
}

extern "C" void kernel_launch(void* const* d_in, const int* in_sizes, int n_in,
                              void* d_out, int out_size, void* d_ws, size_t ws_size,
                              hipStream_t stream)
{
    const float* drive = (const float*)d_in[0];
    const float* Kw    = (const float*)d_in[1];
    float* out         = (float*)d_out;
    // 256 images x 16 tiles = 4096 blocks, 1024 threads (16 waves, 1 block/CU by LDS)
    cml_fused<<<dim3(4096), dim3(1024), 0, stream>>>(drive, Kw, out);
}